// Round 1
// baseline (153.638 us; speedup 1.0000x reference)
//
#include <hip/hip_runtime.h>

// apply_cdna_kernels: out[n,b,c,h,w] = sum_{kh,kw} images[b,h+kh-2,w+kw-2,c] * kernels[b,kh,kw,n]
// images: [64,128,128,3] f32   kernels: [64,5,5,10] f32   out: [10,64,3,128,128] f32

#define B_  64
#define H_  128
#define W_  128
#define C_  3
#define N_  10
#define KH_ 5
#define KW_ 5
#define TH_ 8
#define TW_ 32
#define HALO 2
#define LDS_ROW ((TW_ + 2*HALO) * C_)          // 36*3 = 108 floats per row
#define LDS_ELEMS ((TH_ + 2*HALO) * LDS_ROW)   // 12*108 = 1296 floats

__global__ __launch_bounds__(256) void cdna_apply_kernel(
    const float* __restrict__ images,
    const float* __restrict__ kernels,
    float* __restrict__ out)
{
    __shared__ float s_img[LDS_ELEMS];

    const int tid = threadIdx.x;
    const int bid = blockIdx.x;
    const int b   = bid >> 6;          // 64 tiles per batch image
    const int t   = bid & 63;
    const int by  = t >> 2;            // 16 tiles in H
    const int bx  = t & 3;             // 4 tiles in W
    const int y0  = by * TH_;
    const int x0  = bx * TW_;

    // ---- stage image tile (with halo, zero-padded) into LDS ----
    const long img_base = (long)b * (H_ * W_ * C_);
    #pragma unroll
    for (int i = tid; i < LDS_ELEMS; i += 256) {
        int yy = i / LDS_ROW;
        int r  = i - yy * LDS_ROW;
        int xx = r / C_;
        int c  = r - xx * C_;
        int y  = y0 + yy - HALO;
        int x  = x0 + xx - HALO;
        float v = 0.0f;
        if ((unsigned)y < (unsigned)H_ && (unsigned)x < (unsigned)W_)
            v = images[img_base + (long)y * (W_ * C_) + x * C_ + c];
        s_img[i] = v;
    }
    __syncthreads();

    const int tx = tid & (TW_ - 1);
    const int ty = tid >> 5;

    // block-uniform kernel weights -> scalar loads
    const float* __restrict__ kb = kernels + b * (KH_ * KW_ * N_);

    float acc[N_][C_];
    #pragma unroll
    for (int n = 0; n < N_; ++n)
        #pragma unroll
        for (int c = 0; c < C_; ++c)
            acc[n][c] = 0.0f;

    #pragma unroll
    for (int kh = 0; kh < KH_; ++kh) {
        // read the 15 contiguous floats this thread needs for this row once
        const float* row = &s_img[(ty + kh) * LDS_ROW + tx * C_];
        float p[KW_ * C_];
        #pragma unroll
        for (int i = 0; i < KW_ * C_; ++i) p[i] = row[i];

        #pragma unroll
        for (int kw = 0; kw < KW_; ++kw) {
            #pragma unroll
            for (int n = 0; n < N_; ++n) {
                const float wgt = kb[(kh * KW_ + kw) * N_ + n];  // uniform -> SGPR
                acc[n][0] = fmaf(p[kw * C_ + 0], wgt, acc[n][0]);
                acc[n][1] = fmaf(p[kw * C_ + 1], wgt, acc[n][1]);
                acc[n][2] = fmaf(p[kw * C_ + 2], wgt, acc[n][2]);
            }
        }
    }

    // ---- write out: out[n,b,c,h,w], coalesced in w across lanes ----
    const int h = y0 + ty;
    const int w = x0 + tx;
    const long base = (long)b * (C_ * H_ * W_) + (long)h * W_ + w;
    #pragma unroll
    for (int n = 0; n < N_; ++n) {
        #pragma unroll
        for (int c = 0; c < C_; ++c) {
            out[base + (long)n * ((long)B_ * C_ * H_ * W_) + (long)c * (H_ * W_)] = acc[n][c];
        }
    }
}

extern "C" void kernel_launch(void* const* d_in, const int* in_sizes, int n_in,
                              void* d_out, int out_size, void* d_ws, size_t ws_size,
                              hipStream_t stream) {
    const float* images  = (const float*)d_in[0];
    const float* kernels = (const float*)d_in[1];
    float* out = (float*)d_out;

    const int grid = B_ * (H_ / TH_) * (W_ / TW_);  // 64 * 16 * 4 = 4096
    cdna_apply_kernel<<<grid, 256, 0, stream>>>(images, kernels, out);
}

// Round 2
// 149.048 us; speedup vs baseline: 1.0308x; 1.0308x over previous
//
#include <hip/hip_runtime.h>

// apply_cdna_kernels: out[n,b,c,h,w] = sum_{kh,kw} images[b,h+kh-2,w+kw-2,c] * kernels[b,kh,kw,n]
// images: [64,128,128,3] f32   kernels: [64,5,5,10] f32   out: [10,64,3,128,128] f32

#define B_  64
#define H_  128
#define W_  128
#define C_  3
#define N_  10
#define KH_ 5
#define KW_ 5
#define TH_ 8
#define TW_ 32
#define HALO 2
#define LDS_ROW ((TW_ + 2*HALO) * C_)          // 36*3 = 108 floats per row
#define LDS_ELEMS ((TH_ + 2*HALO) * LDS_ROW)   // 12*108 = 1296 floats

// __launch_bounds__(256,4): cap VGPR at 128 so the 30-acc + 15-p + 50-weight
// live set fits without scratch spill; R1's fully-unrolled body (250 live
// weights) almost certainly spilled -> 153us vs 25us roofline.
__global__ __launch_bounds__(256, 4) void cdna_apply_kernel(
    const float* __restrict__ images,
    const float* __restrict__ kernels,
    float* __restrict__ out)
{
    __shared__ float s_img[LDS_ELEMS];

    const int tid = threadIdx.x;
    const int bid = blockIdx.x;
    const int b   = bid >> 6;          // 64 tiles per batch image
    const int t   = bid & 63;
    const int by  = t >> 2;            // 16 tiles in H
    const int bx  = t & 3;             // 4 tiles in W
    const int y0  = by * TH_;
    const int x0  = bx * TW_;

    // ---- stage image tile (with halo, zero-padded) into LDS ----
    const long img_base = (long)b * (H_ * W_ * C_);
    #pragma unroll
    for (int i = tid; i < LDS_ELEMS; i += 256) {
        int yy = i / LDS_ROW;
        int r  = i - yy * LDS_ROW;
        int xx = r / C_;
        int c  = r - xx * C_;
        int y  = y0 + yy - HALO;
        int x  = x0 + xx - HALO;
        float v = 0.0f;
        if ((unsigned)y < (unsigned)H_ && (unsigned)x < (unsigned)W_)
            v = images[img_base + (long)y * (W_ * C_) + x * C_ + c];
        s_img[i] = v;
    }
    __syncthreads();

    const int tx = tid & (TW_ - 1);
    const int ty = tid >> 5;

    // block-uniform kernel weights -> scalar (s_load) path
    const float* __restrict__ kb = kernels + b * (KH_ * KW_ * N_);

    float acc[N_ * C_];
    #pragma unroll
    for (int i = 0; i < N_ * C_; ++i) acc[i] = 0.0f;

    // Runtime kh loop: bounds the live set to one row of pixels (p[15]) +
    // one row of weights (50) + 30 accs. Do NOT let this unroll.
    #pragma unroll 1
    for (int kh = 0; kh < KH_; ++kh) {
        const float* row = &s_img[(ty + kh) * LDS_ROW + tx * C_];
        float p[KW_ * C_];
        #pragma unroll
        for (int i = 0; i < KW_ * C_; ++i) p[i] = row[i];

        const float* __restrict__ wrow = kb + kh * (KW_ * N_);  // 50 floats, uniform
        #pragma unroll
        for (int kw = 0; kw < KW_; ++kw) {
            #pragma unroll
            for (int n = 0; n < N_; ++n) {
                const float wgt = wrow[kw * N_ + n];   // uniform -> SGPR
                acc[n * C_ + 0] = fmaf(p[kw * C_ + 0], wgt, acc[n * C_ + 0]);
                acc[n * C_ + 1] = fmaf(p[kw * C_ + 1], wgt, acc[n * C_ + 1]);
                acc[n * C_ + 2] = fmaf(p[kw * C_ + 2], wgt, acc[n * C_ + 2]);
            }
        }
    }

    // ---- write out: out[n,b,c,h,w], coalesced in w across lanes ----
    const int h = y0 + ty;
    const int w = x0 + tx;
    float* ob = out + (long)b * (C_ * H_ * W_) + (long)h * W_ + w;
    #pragma unroll
    for (int n = 0; n < N_; ++n) {
        #pragma unroll
        for (int c = 0; c < C_; ++c) {
            ob[(long)n * ((long)B_ * C_ * H_ * W_) + (long)c * (H_ * W_)] = acc[n * C_ + c];
        }
    }
}

extern "C" void kernel_launch(void* const* d_in, const int* in_sizes, int n_in,
                              void* d_out, int out_size, void* d_ws, size_t ws_size,
                              hipStream_t stream) {
    const float* images  = (const float*)d_in[0];
    const float* kernels = (const float*)d_in[1];
    float* out = (float*)d_out;

    const int grid = B_ * (H_ / TH_) * (W_ / TW_);  // 64 * 16 * 4 = 4096
    cdna_apply_kernel<<<grid, 256, 0, stream>>>(images, kernels, out);
}